// Round 19
// baseline (352.120 us; speedup 1.0000x reference)
//
#include <hip/hip_runtime.h>

#define HW 4096
#define CCH 256
#define MOFF 432
#define PTOT 32768
#define PDIM 68
#define PIMG (PDIM*PDIM)      // 4624 padded cells per group-plane (2-wide zero border)

typedef unsigned short u16;
typedef __attribute__((ext_vector_type(8))) short short8;
typedef __attribute__((ext_vector_type(8))) unsigned short u16x8;
typedef __attribute__((ext_vector_type(4))) unsigned short u16x4;
typedef __attribute__((ext_vector_type(4))) float f32x4;

__device__ __forceinline__ u16 f2b(float f){
  unsigned int u = __float_as_uint(f);
  unsigned int rounding = 0x7FFFu + ((u >> 16) & 1u);
  return (u16)((u + rounding) >> 16);
}
__device__ __forceinline__ float b2f(u16 s){
  return __uint_as_float(((unsigned int)s) << 16);
}

// ---------------------------------------------------------------------------
// k_prep: ALL independent prep in ONE launch (R8/R17, proven).
// ---------------------------------------------------------------------------
__global__ __launch_bounds__(256) void k_prep(const float* __restrict__ x,
    const float* __restrict__ w1, const float* __restrict__ w2,
    const float* __restrict__ woff, const float* __restrict__ b1,
    const float* __restrict__ boff,
    const float* __restrict__ gamma, const float* __restrict__ beta,
    const float* __restrict__ mean, const float* __restrict__ var,
    u16* __restrict__ xT, u16* __restrict__ wb_big, u16* __restrict__ wb2,
    float* __restrict__ bnA, float* __restrict__ bnB,
    float* __restrict__ bcomb, u16* __restrict__ h1p){
  __shared__ float tile[64][65];
  const int r = blockIdx.x, t = threadIdx.x;
  if (r < 2048){
    const int pb = (r & 63) * 64, cb = ((r >> 6) & 3) * 64, b = r >> 8;
    const float* src = x + ((size_t)(b * CCH + cb)) * HW + pb;
    #pragma unroll
    for (int pass = 0; pass < 4; ++pass){
      int c_l = pass * 16 + (t >> 4);
      int pq = (t & 15) * 4;
      float4 v = *reinterpret_cast<const float4*>(&src[(size_t)c_l * HW + pq]);
      tile[pq + 0][c_l] = v.x; tile[pq + 1][c_l] = v.y;
      tile[pq + 2][c_l] = v.z; tile[pq + 3][c_l] = v.w;
    }
    __syncthreads();
    #pragma unroll
    for (int pass = 0; pass < 4; ++pass){
      int p_l = pass * 16 + (t >> 4);
      int cq = (t & 15) * 4;
      u16x4 o4;
      #pragma unroll
      for (int j = 0; j < 4; ++j) o4[j] = f2b(tile[p_l][cq + j]);
      *reinterpret_cast<u16x4*>(&xT[((size_t)b * HW + pb + p_l) * CCH + cb + cq]) = o4;
    }
  }
  else if (r < 2304){ int o = r - 2048; wb_big[o*256 + t] = f2b(w1[o*256 + t]); }
  else if (r < 2384){ wb_big[(688 + (r - 2304)) * 256 + t] = 0; }
  else if (r < 2640){ int o = r - 2384; wb2[o*256 + t] = f2b(w2[o*256 + t]); }
  else if (r == 2640){
    if (t < 256){
      float sc = gamma[t] * rsqrtf(var[t] + 1e-5f);
      bnA[t] = sc;
      bnB[t] = beta[t] - mean[t] * sc;
    }
  } else if (r < 3169){
    int n = (r - 2641) * 128 + (t >> 1);   // border cell index
    int seg = t & 1;
    int plane = n / 528, m = n % 528;
    int row, col;
    if (m < 136){ row = m / 68; col = m % 68; }
    else if (m < 272){ int mm = m - 136; row = 66 + mm / 68; col = mm % 68; }
    else { int mm = m - 272; row = 2 + (mm >> 2); int c4 = mm & 3; col = (c4 & 1) + 66 * (c4 >> 1); }
    u16x8 z = {};
    *reinterpret_cast<u16x8*>(&h1p[((size_t)plane * PIMG + row * PDIM + col) * 16 + seg * 8]) = z;
  } else {
    float* wr_ = &tile[0][0];
    float* pb  = wr_ + 256;
    const int j = r - 3169;
    wr_[t] = woff[j * 256 + t];
    __syncthreads();
    float s = 0.f;
    #pragma unroll 8
    for (int m = 0; m < 256; ++m) s += wr_[m] * w1[m * 256 + t];
    wb_big[(256 + j) * 256 + t] = f2b(s);
    pb[t] = wr_[t] * b1[t];
    __syncthreads();
    if (t == 0){
      float bs = boff[j];
      for (int m = 0; m < 256; ++m) bs += pb[m];
      bcomb[j] = bs;
    }
  }
}

// ---------------------------------------------------------------------------
// k_gemm_big (R8/R17, proven): [h1 | om] = xT * wb_big^T. Tile 256x128, BK=64.
// ---------------------------------------------------------------------------
__global__ __launch_bounds__(256, 2) void k_gemm_big(const u16* __restrict__ A,
    const u16* __restrict__ Bw, const float* __restrict__ b1,
    const float* __restrict__ bcomb, u16* __restrict__ h1p,
    u16* __restrict__ om){
  __shared__ __align__(16) u16 smem[34816];   // 69632 B: max(As+Bs staging, C_l)
  u16* As = smem;                   // 256*72
  u16* Bs = smem + 256 * 72;        // 128*72

  const int bid = blockIdx.x;
  const int xcd = bid & 7, s = bid >> 3;
  const int row_local = s / 6, cblk = s % 6;
  const int tm = (row_local * 8 + xcd) * 256;
  const int tn = cblk * 128;

  const int t = threadIdx.x;
  const int lane = t & 63;
  const int wid = t >> 6;
  const int wr = wid >> 1, wc = wid & 1;

  f32x4 acc[8][4] = {};

  for (int kc = 0; kc < 256; kc += 64){
    #pragma unroll
    for (int i = 0; i < 8; ++i){
      int idx = t + i * 256;
      int row = idx >> 3, cq = idx & 7;
      *reinterpret_cast<u16x8*>(&As[row * 72 + cq * 8]) =
        *reinterpret_cast<const u16x8*>(&A[(size_t)(tm + row) * 256 + kc + cq * 8]);
    }
    #pragma unroll
    for (int i = 0; i < 4; ++i){
      int idx = t + i * 256;
      int row = idx >> 3, cq = idx & 7;
      *reinterpret_cast<u16x8*>(&Bs[row * 72 + cq * 8]) =
        *reinterpret_cast<const u16x8*>(&Bw[(size_t)(tn + row) * 256 + kc + cq * 8]);
    }
    __syncthreads();
    #pragma unroll
    for (int kk = 0; kk < 2; ++kk){
      short8 af[8], bf[4];
      #pragma unroll
      for (int m = 0; m < 8; ++m)
        af[m] = *reinterpret_cast<const short8*>(
          &As[(wr * 128 + m * 16 + (lane & 15)) * 72 + kk * 32 + (lane >> 4) * 8]);
      #pragma unroll
      for (int n = 0; n < 4; ++n)
        bf[n] = *reinterpret_cast<const short8*>(
          &Bs[(wc * 64 + n * 16 + (lane & 15)) * 72 + kk * 32 + (lane >> 4) * 8]);
      #pragma unroll
      for (int m = 0; m < 8; ++m)
        #pragma unroll
        for (int n = 0; n < 4; ++n)
          acc[m][n] = __builtin_amdgcn_mfma_f32_16x16x32_bf16(af[m], bf[n], acc[m][n], 0, 0, 0);
    }
    __syncthreads();
  }

  constexpr int CP = 136;
  u16* C_l = smem;
  #pragma unroll
  for (int n = 0; n < 4; ++n){
    int col = wc * 64 + n * 16 + (lane & 15);
    int o = tn + col;
    float bi = (o < 256) ? b1[o] : ((o - 256 < MOFF) ? bcomb[o - 256] : 0.f);
    #pragma unroll
    for (int m = 0; m < 8; ++m){
      int r0 = wr * 128 + m * 16 + ((lane >> 4) << 2);
      #pragma unroll
      for (int j = 0; j < 4; ++j)
        C_l[(r0 + j) * CP + col] = f2b(acc[m][n][j] + bi);
    }
  }
  __syncthreads();
  #pragma unroll
  for (int pass = 0; pass < 16; ++pass){
    int row = pass * 16 + (t >> 4);
    int sg = t & 15;
    int oc = tn + sg * 8;
    int p = tm + row;
    if (tn < 256){
      int bb = p >> 12, ii = (p >> 6) & 63, jj = p & 63;
      size_t dst = ((size_t)(bb * 16 + (oc >> 4)) * PIMG + (ii + 2) * PDIM + jj + 2) * 16 + (oc & 15);
      *reinterpret_cast<u16x8*>(&h1p[dst]) =
        *reinterpret_cast<const u16x8*>(&C_l[row * CP + sg * 8]);
    } else {
      int occ = oc - 256;
      if (occ + 8 <= MOFF)
        *reinterpret_cast<u16x8*>(&om[(size_t)p * MOFF + occ]) =
          *reinterpret_cast<const u16x8*>(&C_l[row * CP + sg * 8]);
    }
  }
}

// ---------------------------------------------------------------------------
// k_sample v5: LDS-tiled. Block = 16 px (4x4 spatial) x 8 groups, 256 thr;
// unit = (px,g) of 2 lanes x 8 ch. Stage the 10x10-cell h1p subtile for 8
// planes (25.7 KB, pitch 1608 -> per-plane distinct banks, 16B aligned) +
// om rows (7.2 KB). Taps read LDS; GLOBAL FALLBACK branch for |off|>=~2
// keeps exact correctness for any input. img->XCD swizzle keeps h1p L2-hot.
// ---------------------------------------------------------------------------
__global__ __launch_bounds__(256, 4) void k_sample(const u16* __restrict__ h1p,
    const u16* __restrict__ om, u16* __restrict__ ydcn){
  __shared__ __align__(16) u16 tile[8 * 1608];   // 25728 B
  __shared__ __align__(16) u16 oms[16 * 224];    // 7168 B (216 used/px)
  const int t = threadIdx.x;
  const int bid = blockIdx.x;
  const int img = bid & 7;
  const int rest = bid >> 3;            // 0..511
  const int g0 = (rest & 1) * 8;
  const int loc = rest >> 1;            // 0..255
  const int i0 = (loc >> 4) * 4, j0 = (loc & 15) * 4;
  const int R0 = max(0, i0 - 1), C0 = max(0, j0 - 1);

  // stage om rows: 16 px x 216 u16 (groups g0..g0+7), 432 16B segs
  for (int s = t; s < 432; s += 256){
    int px = s / 27, sg = s % 27;
    int i = i0 + (px >> 2), j = j0 + (px & 3);
    size_t src = ((size_t)img * 4096 + i * 64 + j) * MOFF + g0 * 27 + sg * 8;
    *reinterpret_cast<u16x8*>(&oms[px * 224 + sg * 8]) =
      *reinterpret_cast<const u16x8*>(&om[src]);
  }
  // stage h1p subtile: 8 planes x 10 rows x 10 cols cells (32B) = 1600 segs
  for (int s = t; s < 1600; s += 256){
    int cell = s >> 1, half = s & 1;
    int g8 = cell / 100, rc = cell % 100;
    int rr = rc / 10, cc = rc % 10;
    int pr = R0 + rr, pc = C0 + cc;
    u16x8 v = {};
    if (pr < 68 && pc < 68)
      v = *reinterpret_cast<const u16x8*>(
        &h1p[((size_t)(img * 16 + g0 + g8) * PIMG + pr * PDIM + pc) * 16 + half * 8]);
    *reinterpret_cast<u16x8*>(&tile[g8 * 1608 + rr * 160 + cc * 16 + half * 8]) = v;
  }
  __syncthreads();

  const int px = t >> 4, g8 = (t >> 1) & 7, ln = t & 1;
  const int i = i0 + (px >> 2), j = j0 + (px & 3);
  const u16* ob = &oms[px * 224 + g8 * 27];
  const u16* tp = &tile[g8 * 1608 + ln * 8];
  const u16* gp = h1p + (size_t)(img * 16 + g0 + g8) * PIMG * 16 + ln * 8;
  const float fi = (float)i, fj = (float)j;

  float acc[8] = {};
  #pragma unroll
  for (int k = 0; k < 9; ++k){
    float oh = b2f(ob[2 * k]), ow = b2f(ob[2 * k + 1]), m = b2f(ob[18 + k]);
    float ph = fi + (float)(k / 3 - 1) + oh;
    float pw = fj + (float)(k % 3 - 1) + ow;
    float h0f = floorf(ph), w0f = floorf(pw);
    float ah = ph - h0f, aw = pw - w0f;
    int h0 = (int)h0f, w0 = (int)w0f;
    int pr = min(max(h0, -2), 64) + 2;
    int pc = min(max(w0, -2), 64) + 2;
    float mh1 = m * ah, mh0 = m - mh1;
    float c01 = mh0 * aw, c00 = mh0 - c01;
    float c11 = mh1 * aw, c10 = mh1 - c11;
    int tr = pr - R0, tc = pc - C0;
    u16x8 t0, t1, b0, b1;
    if ((unsigned)tr <= 8u && (unsigned)tc <= 8u){
      const u16* cb = tp + tr * 160 + tc * 16;
      t0 = *reinterpret_cast<const u16x8*>(cb);
      t1 = *reinterpret_cast<const u16x8*>(cb + 16);
      b0 = *reinterpret_cast<const u16x8*>(cb + 160);
      b1 = *reinterpret_cast<const u16x8*>(cb + 176);
    } else {
      const u16* cb = gp + (pr * PDIM + pc) * 16;
      t0 = *reinterpret_cast<const u16x8*>(cb);
      t1 = *reinterpret_cast<const u16x8*>(cb + 16);
      b0 = *reinterpret_cast<const u16x8*>(cb + PDIM * 16);
      b1 = *reinterpret_cast<const u16x8*>(cb + PDIM * 16 + 16);
    }
    #pragma unroll
    for (int q = 0; q < 8; ++q)
      acc[q] += c00 * b2f(t0[q]) + c01 * b2f(t1[q])
              + c10 * b2f(b0[q]) + c11 * b2f(b1[q]);
  }
  u16x8 o8;
  #pragma unroll
  for (int q = 0; q < 8; ++q) o8[q] = f2b(acc[q]);
  *reinterpret_cast<u16x8*>(&ydcn[((size_t)img * 4096 + i * 64 + j) * 256
                                  + (g0 + g8) * 16 + ln * 8]) = o8;
}

// ---------------------------------------------------------------------------
// k_gemm2 v2 (R17): conv2 + BN + SiLU. Tile 128x128, BK=64.
// ---------------------------------------------------------------------------
__global__ __launch_bounds__(256, 4) void k_gemm2(const u16* __restrict__ A,
    const u16* __restrict__ Bw, const float* __restrict__ bnA,
    const float* __restrict__ bnB, float* __restrict__ out){
  __shared__ __align__(16) u16 smem[(128 + 128) * 72];   // 36864 B
  u16* As = smem;
  u16* Bs = smem + 128 * 72;
  const int t = threadIdx.x;
  const int tm = blockIdx.x * 128;
  const int tn = blockIdx.y * 128;
  const int lane = t & 63;
  const int wid = t >> 6;
  const int wr = wid >> 1, wc = wid & 1;

  f32x4 acc[4][4] = {};

  for (int kc = 0; kc < 256; kc += 64){
    #pragma unroll
    for (int i = 0; i < 4; ++i){
      int idx = t + i * 256;
      int row = idx >> 3, cq = idx & 7;
      *reinterpret_cast<u16x8*>(&As[row * 72 + cq * 8]) =
        *reinterpret_cast<const u16x8*>(&A[(size_t)(tm + row) * 256 + kc + cq * 8]);
    }
    #pragma unroll
    for (int i = 0; i < 4; ++i){
      int idx = t + i * 256;
      int row = idx >> 3, cq = idx & 7;
      *reinterpret_cast<u16x8*>(&Bs[row * 72 + cq * 8]) =
        *reinterpret_cast<const u16x8*>(&Bw[(size_t)(tn + row) * 256 + kc + cq * 8]);
    }
    __syncthreads();
    #pragma unroll
    for (int kk = 0; kk < 2; ++kk){
      short8 af[4], bf[4];
      #pragma unroll
      for (int m = 0; m < 4; ++m)
        af[m] = *reinterpret_cast<const short8*>(
          &As[(wr * 64 + m * 16 + (lane & 15)) * 72 + kk * 32 + (lane >> 4) * 8]);
      #pragma unroll
      for (int n = 0; n < 4; ++n)
        bf[n] = *reinterpret_cast<const short8*>(
          &Bs[(wc * 64 + n * 16 + (lane & 15)) * 72 + kk * 32 + (lane >> 4) * 8]);
      #pragma unroll
      for (int m = 0; m < 4; ++m)
        #pragma unroll
        for (int n = 0; n < 4; ++n)
          acc[m][n] = __builtin_amdgcn_mfma_f32_16x16x32_bf16(af[m], bf[n], acc[m][n], 0, 0, 0);
    }
    __syncthreads();
  }

  const int bimg = tm >> 12;
  const int ploc = tm & 4095;
  #pragma unroll
  for (int n = 0; n < 4; ++n){
    int o = tn + wc * 64 + n * 16 + (lane & 15);
    float sA = bnA[o], sB = bnB[o];
    #pragma unroll
    for (int m = 0; m < 4; ++m){
      int prow = wr * 64 + m * 16 + ((lane >> 4) << 2);
      f32x4 st;
      #pragma unroll
      for (int j = 0; j < 4; ++j){
        float y = acc[m][n][j] * sA + sB;
        st[j] = y / (1.f + expf(-y));
      }
      *reinterpret_cast<f32x4*>(&out[((size_t)(bimg * 256 + o)) * HW + ploc + prow]) = st;
    }
  }
}

extern "C" void kernel_launch(void* const* d_in, const int* in_sizes, int n_in,
                              void* d_out, int out_size, void* d_ws, size_t ws_size,
                              hipStream_t stream) {
  const float* x     = (const float*)d_in[0];
  const float* w1    = (const float*)d_in[1];
  const float* b1    = (const float*)d_in[2];
  const float* woff  = (const float*)d_in[3];
  const float* boff  = (const float*)d_in[4];
  const float* w2    = (const float*)d_in[5];
  const float* gamma = (const float*)d_in[6];
  const float* beta  = (const float*)d_in[7];
  const float* mean  = (const float*)d_in[8];
  const float* var   = (const float*)d_in[9];
  float* out = (float*)d_out;
  (void)in_sizes; (void)n_in; (void)out_size; (void)ws_size;

  u16* h1p    = (u16*)d_ws;                               // 128 planes * 4624 * 32B = 18.9 MB
  u16* om     = h1p + (size_t)128 * PIMG * 16;            // 32768*432 = 28.3 MB
  u16* xT     = om + (size_t)PTOT * MOFF;                 // 32768*256 = 16.8 MB
  u16* ydcn   = xT + (size_t)PTOT * CCH;                  // 32768*256 = 16.8 MB
  u16* wb_big = ydcn + (size_t)PTOT * CCH;                // 768*256 bf16
  u16* wb2    = wb_big + 768 * 256;                       // 256*256
  float* bnA  = (float*)(wb2 + 256 * 256);
  float* bnB  = bnA + 256;
  float* bcomb = bnB + 256;                               // 432 f32

  dim3 blk(256);
  k_prep<<<dim3(3601), blk, 0, stream>>>(x, w1, w2, woff, b1, boff,
                                         gamma, beta, mean, var,
                                         xT, wb_big, wb2, bnA, bnB, bcomb, h1p);
  k_gemm_big<<<dim3(768), blk, 0, stream>>>(xT, wb_big, b1, bcomb, h1p, om);
  k_sample<<<dim3(4096), blk, 0, stream>>>(h1p, om, ydcn);
  k_gemm2<<<dim3(PTOT / 128, 2), blk, 0, stream>>>(ydcn, wb2, bnA, bnB, out);
}